// Round 15
// baseline (235.098 us; speedup 1.0000x reference)
//
#include <hip/hip_runtime.h>

typedef __attribute__((ext_vector_type(8))) short short8;
typedef __attribute__((ext_vector_type(16))) float f32x16;
typedef __attribute__((ext_vector_type(2))) float f32x2;

// d_ws layout (ushort elements):
#define WS_GT   0        // 26*8 = 208 bf16
#define WS_CT   256      // 27*8 = 216 bf16
#define WS_W1T  512      // 256 cols * 13 slots * 8 bf16 = 26624 ushorts (52 KB)

__device__ __forceinline__ unsigned short f2bf(float f) {
    unsigned int u = __float_as_uint(f);
    u = (u + 0x7fffu + ((u >> 16) & 1u)) >> 16;   // RNE
    return (unsigned short)u;
}
__device__ __forceinline__ float bflo(unsigned int w) { return __uint_as_float(w << 16); }
__device__ __forceinline__ float bfhi(unsigned int w) { return __uint_as_float(w & 0xffff0000u); }

// W1 stored transposed [col][13 slots of 8]; 208 B col stride (conflict-free
// for ds_read_b128, verified rounds 5-7/9/11/12/14: 0 conflicts).
__global__ __launch_bounds__(256) void prep_kernel(
    const float* __restrict__ gt, const float* __restrict__ ct,
    const float* __restrict__ W1, unsigned short* __restrict__ ws)
{
    int tid = blockIdx.x * 256 + threadIdx.x;
    if (tid < 208) ws[WS_GT + tid] = f2bf(gt[tid]);
    if (tid < 216) ws[WS_CT + tid] = f2bf(ct[tid]);
    if (tid < 24576) {
        int kl  = tid >> 8;     // logical k 0..95
        int col = tid & 255;    // hidden col 0..255
        int chunk = kl >> 3, j = kl & 7;
        int hi, kk;
        if (chunk < 5)        { hi = 0; kk = chunk; }      // guess letters -> half 0
        else if (chunk < 10)  { hi = 1; kk = chunk - 5; }  // constraint letters -> half 1
        else if (chunk == 10) { hi = 0; kk = 5; }          // presence mean -> half 0
        else                  { hi = 1; kk = 5; }          // absent mean  -> half 1
        int s = kk * 2 + hi;                                // physical k-slot 0..11
        ws[WS_W1T + col * 104 + s * 8 + j] = f2bf(W1[kl * 256 + col]);
    }
}

// Each wave: 64 rows (two 32-row MFMA tiles U,V) x 256 cols; acc 64 AGPR.
// Total regs ~168 <= 170 -> 3 waves/SIMD with LDS 52 KB (no outbuf) x3 <= 160 KB.
__global__ __launch_bounds__(256, 3) void wordle_kernel(
    const int* __restrict__ gidx, const int* __restrict__ cidx,
    const int* __restrict__ pidx, const int* __restrict__ plen,
    const int* __restrict__ aidx, const int* __restrict__ alen,
    const float* __restrict__ b1, const float* __restrict__ W2,
    const float* __restrict__ b2, const unsigned short* __restrict__ ws,
    float* __restrict__ out, int nTiles, int stride)
{
    __shared__ unsigned short w1t[26624];   // 52 KB (sole LDS use)

    // Stage W1T (linear coalesced copy; layout pre-applied in d_ws)
    {
        const uint4* src = (const uint4*)(ws + WS_W1T);
        uint4* dst = (uint4*)w1t;
        int tid = threadIdx.x;
        #pragma unroll
        for (int i = 0; i < 13; ++i) dst[tid + i * 256] = src[tid + i * 256];
    }
    __syncthreads();

    const int lane = threadIdx.x & 63;
    const int wv   = threadIdx.x >> 6;
    const int l31  = lane & 31;
    const int hi   = lane >> 5;
    const unsigned short* gt = ws + WS_GT;
    const unsigned short* ct = ws + WS_CT;
    const unsigned short* tb = hi ? ct : gt;
    const float b2v = b2[0];

    // Hoisted epilogue weights (8 col-tiles of 32)
    float w2r[8], b1r[8];
    #pragma unroll
    for (int nt = 0; nt < 8; ++nt) {
        w2r[nt] = W2[nt * 32 + l31];
        b1r[nt] = b1[nt * 32 + l31];
    }

    // Shared idx regs (reused for U then V)
    int ip0, ip1, ip2, ip3, ip4;
    int s0, s1, s2, s3, s4, s5, s6, s7, s8, s9;
    int lenv;

#define LOADIDX(T, ROFF) do {                                               \
        const int r_ = (T) * 256 + wv * 64 + (ROFF) + l31;                  \
        const int* ip_ = (hi ? cidx : gidx) + r_ * 5;                       \
        ip0 = ip_[0]; ip1 = ip_[1]; ip2 = ip_[2]; ip3 = ip_[3]; ip4 = ip_[4]; \
        const int* si_ = (hi ? aidx : pidx) + r_ * 10;                      \
        s0 = si_[0]; s1 = si_[1]; s2 = si_[2]; s3 = si_[3]; s4 = si_[4];    \
        s5 = si_[5]; s6 = si_[6]; s7 = si_[7]; s8 = si_[8]; s9 = si_[9];    \
        lenv = (hi ? alen : plen)[r_];                                      \
    } while (0)

    // Packed masked mean from 10 uint4 e-regs -> short8 (r12/r14-verified math)
#define MEAN(A5, E, LEN) do {                                               \
        f32x2 m0 = {0.f, 0.f}, m1 = {0.f, 0.f}, m2 = {0.f, 0.f}, m3 = {0.f, 0.f}; \
        _Pragma("unroll") for (int k = 0; k < 10; ++k) {                    \
            const float w = (k < (LEN)) ? 1.f : 0.f;                        \
            const f32x2 wv2 = {w, w};                                       \
            f32x2 v0 = {bflo((E)[k].x), bfhi((E)[k].x)};                    \
            f32x2 v1 = {bflo((E)[k].y), bfhi((E)[k].y)};                    \
            f32x2 v2 = {bflo((E)[k].z), bfhi((E)[k].z)};                    \
            f32x2 v3 = {bflo((E)[k].w), bfhi((E)[k].w)};                    \
            m0 += wv2 * v0; m1 += wv2 * v1; m2 += wv2 * v2; m3 += wv2 * v3; \
        }                                                                   \
        const float scl = ((LEN) > 0) ? (1.f / (float)(LEN)) : 0.f;         \
        (A5)[0] = (short)f2bf(m0[0] * scl); (A5)[1] = (short)f2bf(m0[1] * scl); \
        (A5)[2] = (short)f2bf(m1[0] * scl); (A5)[3] = (short)f2bf(m1[1] * scl); \
        (A5)[4] = (short)f2bf(m2[0] * scl); (A5)[5] = (short)f2bf(m2[1] * scl); \
        (A5)[6] = (short)f2bf(m3[0] * scl); (A5)[7] = (short)f2bf(m3[1] * scl); \
    } while (0)

    // f32x2 split-register butterfly over 32 lanes (r12/r14-verified)
#define BUTTERFLY(PART, P5) do {                                            \
        const int b_ = (l31 >> 4) & 1, c_ = (l31 >> 3) & 1,                 \
                  d_ = (l31 >> 2) & 1, e_ = (l31 >> 1) & 1;                 \
        f32x2 q1[4], q2[2], q3;                                             \
        float p4;                                                           \
        _Pragma("unroll") for (int i = 0; i < 4; ++i) {                     \
            f32x2 keep = b_ ? (PART)[4 + i] : (PART)[i];                    \
            f32x2 send = b_ ? (PART)[i]     : (PART)[4 + i];                \
            f32x2 got;                                                      \
            got[0] = __shfl_xor(send[0], 16, 64);                           \
            got[1] = __shfl_xor(send[1], 16, 64);                           \
            q1[i] = keep + got;                                             \
        }                                                                   \
        _Pragma("unroll") for (int i = 0; i < 2; ++i) {                     \
            f32x2 keep = c_ ? q1[2 + i] : q1[i];                            \
            f32x2 send = c_ ? q1[i]     : q1[2 + i];                        \
            f32x2 got;                                                      \
            got[0] = __shfl_xor(send[0], 8, 64);                            \
            got[1] = __shfl_xor(send[1], 8, 64);                            \
            q2[i] = keep + got;                                             \
        }                                                                   \
        {                                                                   \
            f32x2 keep = d_ ? q2[1] : q2[0];                                \
            f32x2 send = d_ ? q2[0] : q2[1];                                \
            f32x2 got;                                                      \
            got[0] = __shfl_xor(send[0], 4, 64);                            \
            got[1] = __shfl_xor(send[1], 4, 64);                            \
            q3 = keep + got;                                                \
        }                                                                   \
        {                                                                   \
            float keep = e_ ? q3[1] : q3[0];                                \
            float send = e_ ? q3[0] : q3[1];                                \
            p4 = keep + __shfl_xor(send, 2, 64);                            \
        }                                                                   \
        (P5) = p4 + __shfl_xor(p4, 1, 64);                                  \
    } while (0)

    for (int t = blockIdx.x; t < nTiles; t += stride) {

        // ---------- gathers: U then V (idx regs reused) ----------
        LOADIDX(t, 0);
        short8 aU0 = *(const short8*)(tb + ip0 * 8);
        short8 aU1 = *(const short8*)(tb + ip1 * 8);
        short8 aU2 = *(const short8*)(tb + ip2 * 8);
        short8 aU3 = *(const short8*)(tb + ip3 * 8);
        short8 aU4 = *(const short8*)(tb + ip4 * 8);
        uint4 eU[10];
        eU[0] = *(const uint4*)(gt + s0 * 8); eU[1] = *(const uint4*)(gt + s1 * 8);
        eU[2] = *(const uint4*)(gt + s2 * 8); eU[3] = *(const uint4*)(gt + s3 * 8);
        eU[4] = *(const uint4*)(gt + s4 * 8); eU[5] = *(const uint4*)(gt + s5 * 8);
        eU[6] = *(const uint4*)(gt + s6 * 8); eU[7] = *(const uint4*)(gt + s7 * 8);
        eU[8] = *(const uint4*)(gt + s8 * 8); eU[9] = *(const uint4*)(gt + s9 * 8);
        const int lenU = lenv;

        LOADIDX(t, 32);
        short8 aV0 = *(const short8*)(tb + ip0 * 8);
        short8 aV1 = *(const short8*)(tb + ip1 * 8);
        short8 aV2 = *(const short8*)(tb + ip2 * 8);
        short8 aV3 = *(const short8*)(tb + ip3 * 8);
        short8 aV4 = *(const short8*)(tb + ip4 * 8);
        uint4 eV[10];
        eV[0] = *(const uint4*)(gt + s0 * 8); eV[1] = *(const uint4*)(gt + s1 * 8);
        eV[2] = *(const uint4*)(gt + s2 * 8); eV[3] = *(const uint4*)(gt + s3 * 8);
        eV[4] = *(const uint4*)(gt + s4 * 8); eV[5] = *(const uint4*)(gt + s5 * 8);
        eV[6] = *(const uint4*)(gt + s6 * 8); eV[7] = *(const uint4*)(gt + s7 * 8);
        eV[8] = *(const uint4*)(gt + s8 * 8); eV[9] = *(const uint4*)(gt + s9 * 8);
        const int lenV = lenv;

        // ---------- masked means ----------
        short8 aU5, aV5;
        MEAN(aU5, eU, lenU);
        MEAN(aV5, eV, lenV);

        // ---------- MFMA: 4 quarter-passes over cols; each bv feeds U and V ----------
        f32x2 partU[8], partV[8];
        #pragma unroll
        for (int i = 0; i < 8; ++i) {
            partU[i][0] = 0.f; partU[i][1] = 0.f;
            partV[i][0] = 0.f; partV[i][1] = 0.f;
        }

        #pragma unroll
        for (int q = 0; q < 4; ++q) {
            f32x16 accU[2], accV[2];
            #pragma unroll
            for (int j = 0; j < 2; ++j)
                #pragma unroll
                for (int r = 0; r < 16; ++r) { accU[j][r] = 0.f; accV[j][r] = 0.f; }

            #pragma unroll
            for (int kk = 0; kk < 6; ++kk) {
                const short8 avU = (kk == 0) ? aU0 : (kk == 1) ? aU1 : (kk == 2) ? aU2
                                 : (kk == 3) ? aU3 : (kk == 4) ? aU4 : aU5;
                const short8 avV = (kk == 0) ? aV0 : (kk == 1) ? aV1 : (kk == 2) ? aV2
                                 : (kk == 3) ? aV3 : (kk == 4) ? aV4 : aV5;
                const int s = kk * 2 + hi;
                #pragma unroll
                for (int j = 0; j < 2; ++j) {
                    const int col = (q * 2 + j) * 32 + l31;
                    short8 bv = *(const short8*)(&w1t[col * 104 + s * 8]);
                    accU[j] = __builtin_amdgcn_mfma_f32_32x32x16_bf16(avU, bv, accU[j], 0, 0, 0);
                    accV[j] = __builtin_amdgcn_mfma_f32_32x32x16_bf16(avV, bv, accV[j], 0, 0, 0);
                }
            }

            // quarter epilogue: b1-add + relu + W2-dot (packed)
            #pragma unroll
            for (int j = 0; j < 2; ++j) {
                const int nt = q * 2 + j;
                const f32x2 w2v = {w2r[nt], w2r[nt]};
                const f32x2 b1v = {b1r[nt], b1r[nt]};
                const f32x2 z = {0.f, 0.f};
                #pragma unroll
                for (int i = 0; i < 8; ++i) {
                    f32x2 hU = {accU[j][2 * i], accU[j][2 * i + 1]};
                    f32x2 hV = {accV[j][2 * i], accV[j][2 * i + 1]};
                    hU = __builtin_elementwise_max(hU + b1v, z);
                    hV = __builtin_elementwise_max(hV + b1v, z);
                    partU[i] += hU * w2v;
                    partV[i] += hV * w2v;
                }
            }
        }

        // ---------- butterflies + direct in-line-permuted store ----------
        // Even lanes hold the final sums; each store's 32 addresses permute
        // one 128 B line -> fully coalesced without an LDS round-trip.
        float p5U, p5V;
        BUTTERFLY(partU, p5U);
        BUTTERFLY(partV, p5V);
        if (!(lane & 1)) {
            const int r = l31 >> 1;
            const int ro = 4 * hi + (r & 3) + 8 * (r >> 2);
            out[t * 256 + wv * 64 + ro]      = p5U + b2v;
            out[t * 256 + wv * 64 + 32 + ro] = p5V + b2v;
        }
    }
#undef LOADIDX
#undef MEAN
#undef BUTTERFLY
}

extern "C" void kernel_launch(void* const* d_in, const int* in_sizes, int n_in,
                              void* d_out, int out_size, void* d_ws, size_t ws_size,
                              hipStream_t stream) {
    const int*   gidx = (const int*)d_in[0];
    const int*   cidx = (const int*)d_in[1];
    const int*   pidx = (const int*)d_in[2];
    const int*   plen = (const int*)d_in[3];
    const int*   aidx = (const int*)d_in[4];
    const int*   alen = (const int*)d_in[5];
    const float* gt   = (const float*)d_in[6];
    const float* ct   = (const float*)d_in[7];
    const float* W1   = (const float*)d_in[8];
    const float* b1   = (const float*)d_in[9];
    const float* W2   = (const float*)d_in[10];
    const float* b2   = (const float*)d_in[11];
    float* out = (float*)d_out;
    unsigned short* ws = (unsigned short*)d_ws;

    const int B = in_sizes[0] / 5;          // 1048576
    prep_kernel<<<96, 256, 0, stream>>>(gt, ct, W1, ws);

    const int nTiles = B / 256;             // 4096 block-tiles of 256 rows
    const int blocks = 768;                 // 3 blocks/CU (52 KB x 3 <= 160 KB)
    wordle_kernel<<<blocks, 256, 0, stream>>>(gidx, cidx, pidx, plen, aidx, alen,
                                              b1, W2, b2, ws, out, nTiles, blocks);
}

// Round 16
// 77.347 us; speedup vs baseline: 3.0395x; 3.0395x over previous
//
#include <hip/hip_runtime.h>

typedef __attribute__((ext_vector_type(8))) short short8;
typedef __attribute__((ext_vector_type(16))) float f32x16;
typedef __attribute__((ext_vector_type(2))) float f32x2;

// d_ws layout (ushort elements):
#define WS_GT   0        // 26*8 = 208 bf16
#define WS_CT   256      // 27*8 = 216 bf16
#define WS_W1T  512      // 256 cols * 13 slots * 8 bf16 = 26624 ushorts (52 KB)
                         // slots 0-11: W1T data (s = kk*2 + hi); slot 12: pad

__device__ __forceinline__ unsigned short f2bf(float f) {
    unsigned int u = __float_as_uint(f);
    u = (u + 0x7fffu + ((u >> 16) & 1u)) >> 16;   // RNE
    return (unsigned short)u;
}
__device__ __forceinline__ float bflo(unsigned int w) { return __uint_as_float(w << 16); }
__device__ __forceinline__ float bfhi(unsigned int w) { return __uint_as_float(w & 0xffff0000u); }

// W1 stored transposed [col][13 slots of 8]; 208 B col stride (odd multiple of
// 16 B -> ds_read_b128 conflict-free, verified: 0 conflicts across rounds).
__global__ __launch_bounds__(256) void prep_kernel(
    const float* __restrict__ gt, const float* __restrict__ ct,
    const float* __restrict__ W1, unsigned short* __restrict__ ws)
{
    int tid = blockIdx.x * 256 + threadIdx.x;
    if (tid < 208) ws[WS_GT + tid] = f2bf(gt[tid]);
    if (tid < 216) ws[WS_CT + tid] = f2bf(ct[tid]);
    if (tid < 24576) {
        int kl  = tid >> 8;     // logical k 0..95
        int col = tid & 255;    // hidden col 0..255
        int chunk = kl >> 3, j = kl & 7;
        int hi, kk;
        if (chunk < 5)        { hi = 0; kk = chunk; }      // guess letters -> half 0
        else if (chunk < 10)  { hi = 1; kk = chunk - 5; }  // constraint letters -> half 1
        else if (chunk == 10) { hi = 0; kk = 5; }          // presence mean -> half 0
        else                  { hi = 1; kk = 5; }          // absent mean  -> half 1
        int s = kk * 2 + hi;                                // physical k-slot 0..11
        ws[WS_W1T + col * 104 + s * 8 + j] = f2bf(W1[kl * 256 + col]);
    }
}

__global__ __launch_bounds__(256, 2) void wordle_kernel(
    const int* __restrict__ gidx, const int* __restrict__ cidx,
    const int* __restrict__ pidx, const int* __restrict__ plen,
    const int* __restrict__ aidx, const int* __restrict__ alen,
    const float* __restrict__ b1, const float* __restrict__ W2,
    const float* __restrict__ b2, const unsigned short* __restrict__ ws,
    float* __restrict__ out, int tilesPerBlock)
{
    __shared__ unsigned short w1t[26624];   // 52 KB
    __shared__ float outbuf[128];           // 4 waves * 32 rows

    // Stage W1T (linear coalesced copy; layout pre-applied in d_ws)
    {
        const uint4* src = (const uint4*)(ws + WS_W1T);
        uint4* dst = (uint4*)w1t;
        int tid = threadIdx.x;
        #pragma unroll
        for (int i = 0; i < 13; ++i) dst[tid + i * 256] = src[tid + i * 256];
    }
    __syncthreads();

    const int lane = threadIdx.x & 63;
    const int wv   = threadIdx.x >> 6;
    const int l31  = lane & 31;
    const int hi   = lane >> 5;
    const unsigned short* gt = ws + WS_GT;
    const unsigned short* ct = ws + WS_CT;
    const unsigned short* tb = hi ? ct : gt;
    const float b2v = b2[0];

    // Hoisted epilogue weights (8 col-tiles of 32)
    float w2r[8], b1r[8];
    #pragma unroll
    for (int nt = 0; nt < 8; ++nt) {
        w2r[nt] = W2[nt * 32 + l31];
        b1r[nt] = b1[nt * 32 + l31];
    }

    // Prefetched per-row indices for the CURRENT tile (scalar loads — aligned)
    int ip0, ip1, ip2, ip3, ip4;
    int s0, s1, s2, s3, s4, s5, s6, s7, s8, s9;
    int lenv;

#define LOADIDX(T) do {                                                     \
        const int r_ = (blockIdx.x * tilesPerBlock + (T)) * 128 + wv * 32 + l31; \
        const int* ip_ = (hi ? cidx : gidx) + r_ * 5;                       \
        ip0 = ip_[0]; ip1 = ip_[1]; ip2 = ip_[2]; ip3 = ip_[3]; ip4 = ip_[4]; \
        const int* si_ = (hi ? aidx : pidx) + r_ * 10;                      \
        s0 = si_[0]; s1 = si_[1]; s2 = si_[2]; s3 = si_[3]; s4 = si_[4];    \
        s5 = si_[5]; s6 = si_[6]; s7 = si_[7]; s8 = si_[8]; s9 = si_[9];    \
        lenv = (hi ? alen : plen)[r_];                                      \
    } while (0)

    LOADIDX(0);

    for (int t = 0; t < tilesPerBlock; ++t) {
        const int tile = blockIdx.x * tilesPerBlock + t;

        // ---------- gather: issue all table loads for this tile ----------
        short8 a0 = *(const short8*)(tb + ip0 * 8);
        short8 a1 = *(const short8*)(tb + ip1 * 8);
        short8 a2 = *(const short8*)(tb + ip2 * 8);
        short8 a3 = *(const short8*)(tb + ip3 * 8);
        short8 a4 = *(const short8*)(tb + ip4 * 8);
        uint4 e0 = *(const uint4*)(gt + s0 * 8);
        uint4 e1 = *(const uint4*)(gt + s1 * 8);
        uint4 e2 = *(const uint4*)(gt + s2 * 8);
        uint4 e3 = *(const uint4*)(gt + s3 * 8);
        uint4 e4 = *(const uint4*)(gt + s4 * 8);
        uint4 e5 = *(const uint4*)(gt + s5 * 8);
        uint4 e6 = *(const uint4*)(gt + s6 * 8);
        uint4 e7 = *(const uint4*)(gt + s7 * 8);
        uint4 e8 = *(const uint4*)(gt + s8 * 8);
        uint4 e9 = *(const uint4*)(gt + s9 * 8);
        const int len = lenv;

        // ---------- prefetch next tile's indices (hides under MFMA) ----------
        if (t + 1 < tilesPerBlock) LOADIDX(t + 1);

        // ---------- masked mean -> a5 (packed f32 pairs) ----------
        short8 a5;
        {
            f32x2 m0 = {0.f, 0.f}, m1 = {0.f, 0.f}, m2 = {0.f, 0.f}, m3 = {0.f, 0.f};
            uint4 ev[10] = {e0,e1,e2,e3,e4,e5,e6,e7,e8,e9};
            #pragma unroll
            for (int k = 0; k < 10; ++k) {
                const float w = (k < len) ? 1.f : 0.f;
                const f32x2 wv2 = {w, w};
                f32x2 v0 = {bflo(ev[k].x), bfhi(ev[k].x)};
                f32x2 v1 = {bflo(ev[k].y), bfhi(ev[k].y)};
                f32x2 v2 = {bflo(ev[k].z), bfhi(ev[k].z)};
                f32x2 v3 = {bflo(ev[k].w), bfhi(ev[k].w)};
                m0 += wv2 * v0; m1 += wv2 * v1; m2 += wv2 * v2; m3 += wv2 * v3;
            }
            const float scl = (len > 0) ? (1.f / (float)len) : 0.f;
            a5[0] = (short)f2bf(m0[0] * scl); a5[1] = (short)f2bf(m0[1] * scl);
            a5[2] = (short)f2bf(m1[0] * scl); a5[3] = (short)f2bf(m1[1] * scl);
            a5[4] = (short)f2bf(m2[0] * scl); a5[5] = (short)f2bf(m2[1] * scl);
            a5[6] = (short)f2bf(m3[0] * scl); a5[7] = (short)f2bf(m3[1] * scl);
        }

        // ---------- MFMA: 32 rows x 256 cols, K=96, single pass acc[8] ----------
        f32x16 acc[8];
        #pragma unroll
        for (int nt = 0; nt < 8; ++nt)
            #pragma unroll
            for (int r = 0; r < 16; ++r) acc[nt][r] = 0.f;

        #pragma unroll
        for (int kk = 0; kk < 6; ++kk) {
            const short8 av = (kk == 0) ? a0 : (kk == 1) ? a1 : (kk == 2) ? a2
                           : (kk == 3) ? a3 : (kk == 4) ? a4 : a5;
            const int s = kk * 2 + hi;
            #pragma unroll
            for (int nt = 0; nt < 8; ++nt) {
                const int col = nt * 32 + l31;
                short8 bv = *(const short8*)(&w1t[col * 104 + s * 8]);
                acc[nt] = __builtin_amdgcn_mfma_f32_32x32x16_bf16(av, bv, acc[nt], 0, 0, 0);
            }
        }

        // ---------- epilogue: b1-add + relu + W2-dot, packed f32 pairs ----------
        f32x2 part2[8];
        #pragma unroll
        for (int i = 0; i < 8; ++i) { part2[i][0] = 0.f; part2[i][1] = 0.f; }
        #pragma unroll
        for (int nt = 0; nt < 8; ++nt) {
            const f32x2 w2v = {w2r[nt], w2r[nt]};
            const f32x2 b1v = {b1r[nt], b1r[nt]};
            const f32x2 z = {0.f, 0.f};
            #pragma unroll
            for (int i = 0; i < 8; ++i) {
                f32x2 h = {acc[nt][2 * i], acc[nt][2 * i + 1]};
                h = __builtin_elementwise_max(h + b1v, z);
                part2[i] += h * w2v;
            }
        }

        // ---------- split-register butterfly reduce over 32 lanes ----------
        // (operates on float2 pairs; element r = part2[r>>1][r&1])
        const int b_ = (l31 >> 4) & 1, c_ = (l31 >> 3) & 1,
                  d_ = (l31 >> 2) & 1, e_ = (l31 >> 1) & 1;
        f32x2 q1[4], q2[2], q3;
        float p4, p5;
        #pragma unroll
        for (int i = 0; i < 4; ++i) {          // exchange r<8 vs r>=8
            f32x2 keep = b_ ? part2[4 + i] : part2[i];
            f32x2 send = b_ ? part2[i]     : part2[4 + i];
            f32x2 got;
            got[0] = __shfl_xor(send[0], 16, 64);
            got[1] = __shfl_xor(send[1], 16, 64);
            q1[i] = keep + got;
        }
        #pragma unroll
        for (int i = 0; i < 2; ++i) {          // exchange r<4 vs r>=4
            f32x2 keep = c_ ? q1[2 + i] : q1[i];
            f32x2 send = c_ ? q1[i]     : q1[2 + i];
            f32x2 got;
            got[0] = __shfl_xor(send[0], 8, 64);
            got[1] = __shfl_xor(send[1], 8, 64);
            q2[i] = keep + got;
        }
        {                                       // exchange r<2 vs r>=2
            f32x2 keep = d_ ? q2[1] : q2[0];
            f32x2 send = d_ ? q2[0] : q2[1];
            f32x2 got;
            got[0] = __shfl_xor(send[0], 4, 64);
            got[1] = __shfl_xor(send[1], 4, 64);
            q3 = keep + got;
        }
        {                                       // exchange r=0 vs r=1 (inside float2)
            float keep = e_ ? q3[1] : q3[0];
            float send = e_ ? q3[0] : q3[1];
            p4 = keep + __shfl_xor(send, 2, 64);
        }
        p5 = p4 + __shfl_xor(p4, 1, 64);
        // even lane l31 holds the full sum for r = l31>>1 (row = (r&3)+8*(r>>2)+4*hi)

        // ---------- coalesced store via LDS transpose (512 B staging) ----------
        if (!(lane & 1)) {
            const int r = l31 >> 1;
            outbuf[wv * 32 + 4 * hi + (r & 3) + 8 * (r >> 2)] = p5 + b2v;
        }
        asm volatile("s_waitcnt lgkmcnt(0)" ::: "memory");
        if (lane < 32) {
            out[tile * 128 + wv * 32 + lane] = outbuf[wv * 32 + lane];
        }
    }
#undef LOADIDX
}

extern "C" void kernel_launch(void* const* d_in, const int* in_sizes, int n_in,
                              void* d_out, int out_size, void* d_ws, size_t ws_size,
                              hipStream_t stream) {
    const int*   gidx = (const int*)d_in[0];
    const int*   cidx = (const int*)d_in[1];
    const int*   pidx = (const int*)d_in[2];
    const int*   plen = (const int*)d_in[3];
    const int*   aidx = (const int*)d_in[4];
    const int*   alen = (const int*)d_in[5];
    const float* gt   = (const float*)d_in[6];
    const float* ct   = (const float*)d_in[7];
    const float* W1   = (const float*)d_in[8];
    const float* b1   = (const float*)d_in[9];
    const float* W2   = (const float*)d_in[10];
    const float* b2   = (const float*)d_in[11];
    float* out = (float*)d_out;
    unsigned short* ws = (unsigned short*)d_ws;

    const int B = in_sizes[0] / 5;          // 1048576
    prep_kernel<<<96, 256, 0, stream>>>(gt, ct, W1, ws);

    const int tilesTotal = B / 128;         // 8192 block-tiles of 128 rows
    int tpb = 16;                           // 512 persistent blocks = 2/CU
    while (tpb > 1 && (tilesTotal % tpb)) tpb >>= 1;
    const int blocks = tilesTotal / tpb;
    wordle_kernel<<<blocks, 256, 0, stream>>>(gidx, cidx, pidx, plen, aidx, alen,
                                              b1, W2, b2, ws, out, tpb);
}

// Round 17
// 76.903 us; speedup vs baseline: 3.0571x; 1.0058x over previous
//
#include <hip/hip_runtime.h>

typedef __attribute__((ext_vector_type(8))) short short8;
typedef __attribute__((ext_vector_type(16))) float f32x16;
typedef __attribute__((ext_vector_type(2))) float f32x2;

// d_ws layout (ushort elements):
#define WS_GT   0        // 26*8 = 208 bf16
#define WS_CT   256      // 27*8 = 216 bf16
#define WS_W1T  512      // 256 cols * 13 slots * 8 bf16 = 26624 ushorts (52 KB)
                         // slots 0-11: W1T data (s = kk*2 + hi); slot 12: pad

__device__ __forceinline__ unsigned short f2bf(float f) {
    unsigned int u = __float_as_uint(f);
    u = (u + 0x7fffu + ((u >> 16) & 1u)) >> 16;   // RNE
    return (unsigned short)u;
}
__device__ __forceinline__ float bflo(unsigned int w) { return __uint_as_float(w << 16); }
__device__ __forceinline__ float bfhi(unsigned int w) { return __uint_as_float(w & 0xffff0000u); }

// W1 stored transposed [col][13 slots of 8]; 208 B col stride (odd multiple of
// 16 B -> ds_read_b128 conflict-free, verified: 0 conflicts across rounds).
__global__ __launch_bounds__(256) void prep_kernel(
    const float* __restrict__ gt, const float* __restrict__ ct,
    const float* __restrict__ W1, unsigned short* __restrict__ ws)
{
    int tid = blockIdx.x * 256 + threadIdx.x;
    if (tid < 208) ws[WS_GT + tid] = f2bf(gt[tid]);
    if (tid < 216) ws[WS_CT + tid] = f2bf(ct[tid]);
    if (tid < 24576) {
        int kl  = tid >> 8;     // logical k 0..95
        int col = tid & 255;    // hidden col 0..255
        int chunk = kl >> 3, j = kl & 7;
        int hi, kk;
        if (chunk < 5)        { hi = 0; kk = chunk; }      // guess letters -> half 0
        else if (chunk < 10)  { hi = 1; kk = chunk - 5; }  // constraint letters -> half 1
        else if (chunk == 10) { hi = 0; kk = 5; }          // presence mean -> half 0
        else                  { hi = 1; kk = 5; }          // absent mean  -> half 1
        int s = kk * 2 + hi;                                // physical k-slot 0..11
        ws[WS_W1T + col * 104 + s * 8 + j] = f2bf(W1[kl * 256 + col]);
    }
}

__global__ __launch_bounds__(256, 2) void wordle_kernel(
    const int* __restrict__ gidx, const int* __restrict__ cidx,
    const int* __restrict__ pidx, const int* __restrict__ plen,
    const int* __restrict__ aidx, const int* __restrict__ alen,
    const float* __restrict__ b1, const float* __restrict__ W2,
    const float* __restrict__ b2, const unsigned short* __restrict__ ws,
    float* __restrict__ out, int tilesPerBlock)
{
    __shared__ unsigned short w1t[26624];   // 52 KB
    __shared__ float outbuf[128];           // 4 waves * 32 rows

    // Stage W1T (linear coalesced copy; layout pre-applied in d_ws)
    {
        const uint4* src = (const uint4*)(ws + WS_W1T);
        uint4* dst = (uint4*)w1t;
        int tid = threadIdx.x;
        #pragma unroll
        for (int i = 0; i < 13; ++i) dst[tid + i * 256] = src[tid + i * 256];
    }
    __syncthreads();

    const int lane = threadIdx.x & 63;
    const int wv   = threadIdx.x >> 6;
    const int l31  = lane & 31;
    const int hi   = lane >> 5;
    const unsigned short* gt = ws + WS_GT;
    const unsigned short* ct = ws + WS_CT;
    const unsigned short* tb = hi ? ct : gt;
    const float b2v = b2[0];

    // Hoisted epilogue weights (8 col-tiles of 32)
    float w2r[8], b1r[8];
    #pragma unroll
    for (int nt = 0; nt < 8; ++nt) {
        w2r[nt] = W2[nt * 32 + l31];
        b1r[nt] = b1[nt * 32 + l31];
    }

    // Prefetched per-row indices for the CURRENT tile (scalar loads — aligned)
    int ip0, ip1, ip2, ip3, ip4;
    int s0, s1, s2, s3, s4, s5, s6, s7, s8, s9;
    int lenv;

#define LOADIDX(T) do {                                                     \
        const int r_ = (blockIdx.x * tilesPerBlock + (T)) * 128 + wv * 32 + l31; \
        const int* ip_ = (hi ? cidx : gidx) + r_ * 5;                       \
        ip0 = ip_[0]; ip1 = ip_[1]; ip2 = ip_[2]; ip3 = ip_[3]; ip4 = ip_[4]; \
        const int* si_ = (hi ? aidx : pidx) + r_ * 10;                      \
        s0 = si_[0]; s1 = si_[1]; s2 = si_[2]; s3 = si_[3]; s4 = si_[4];    \
        s5 = si_[5]; s6 = si_[6]; s7 = si_[7]; s8 = si_[8]; s9 = si_[9];    \
        lenv = (hi ? alen : plen)[r_];                                      \
    } while (0)

    LOADIDX(0);

    for (int t = 0; t < tilesPerBlock; ++t) {
        const int tile = blockIdx.x * tilesPerBlock + t;

        // ---------- gather: issue all table loads for this tile ----------
        short8 a0 = *(const short8*)(tb + ip0 * 8);
        short8 a1 = *(const short8*)(tb + ip1 * 8);
        short8 a2 = *(const short8*)(tb + ip2 * 8);
        short8 a3 = *(const short8*)(tb + ip3 * 8);
        short8 a4 = *(const short8*)(tb + ip4 * 8);
        uint4 e0 = *(const uint4*)(gt + s0 * 8);
        uint4 e1 = *(const uint4*)(gt + s1 * 8);
        uint4 e2 = *(const uint4*)(gt + s2 * 8);
        uint4 e3 = *(const uint4*)(gt + s3 * 8);
        uint4 e4 = *(const uint4*)(gt + s4 * 8);
        uint4 e5 = *(const uint4*)(gt + s5 * 8);
        uint4 e6 = *(const uint4*)(gt + s6 * 8);
        uint4 e7 = *(const uint4*)(gt + s7 * 8);
        uint4 e8 = *(const uint4*)(gt + s8 * 8);
        uint4 e9 = *(const uint4*)(gt + s9 * 8);
        const int len = lenv;

        // ---------- prefetch next tile's indices (hides under MFMA) ----------
        if (t + 1 < tilesPerBlock) LOADIDX(t + 1);

        // ---------- masked mean -> a5 (packed f32 pairs) ----------
        short8 a5;
        {
            f32x2 m0 = {0.f, 0.f}, m1 = {0.f, 0.f}, m2 = {0.f, 0.f}, m3 = {0.f, 0.f};
            uint4 ev[10] = {e0,e1,e2,e3,e4,e5,e6,e7,e8,e9};
            #pragma unroll
            for (int k = 0; k < 10; ++k) {
                const float w = (k < len) ? 1.f : 0.f;
                const f32x2 wv2 = {w, w};
                f32x2 v0 = {bflo(ev[k].x), bfhi(ev[k].x)};
                f32x2 v1 = {bflo(ev[k].y), bfhi(ev[k].y)};
                f32x2 v2 = {bflo(ev[k].z), bfhi(ev[k].z)};
                f32x2 v3 = {bflo(ev[k].w), bfhi(ev[k].w)};
                m0 += wv2 * v0; m1 += wv2 * v1; m2 += wv2 * v2; m3 += wv2 * v3;
            }
            const float scl = (len > 0) ? (1.f / (float)len) : 0.f;
            a5[0] = (short)f2bf(m0[0] * scl); a5[1] = (short)f2bf(m0[1] * scl);
            a5[2] = (short)f2bf(m1[0] * scl); a5[3] = (short)f2bf(m1[1] * scl);
            a5[4] = (short)f2bf(m2[0] * scl); a5[5] = (short)f2bf(m2[1] * scl);
            a5[6] = (short)f2bf(m3[0] * scl); a5[7] = (short)f2bf(m3[1] * scl);
        }

        // ---------- MFMA: 32 rows x 256 cols, K=96, single pass acc[8] ----------
        // setprio(1): waves run unsynchronized (no per-tile barrier); boost the
        // wave in its MFMA burst so its ds_read+MFMA chain wins issue arbitration
        // over co-resident waves' gather/mean phases (T5 mechanism, m191).
        f32x16 acc[8];
        #pragma unroll
        for (int nt = 0; nt < 8; ++nt)
            #pragma unroll
            for (int r = 0; r < 16; ++r) acc[nt][r] = 0.f;

        __builtin_amdgcn_s_setprio(1);
        #pragma unroll
        for (int kk = 0; kk < 6; ++kk) {
            const short8 av = (kk == 0) ? a0 : (kk == 1) ? a1 : (kk == 2) ? a2
                           : (kk == 3) ? a3 : (kk == 4) ? a4 : a5;
            const int s = kk * 2 + hi;
            #pragma unroll
            for (int nt = 0; nt < 8; ++nt) {
                const int col = nt * 32 + l31;
                short8 bv = *(const short8*)(&w1t[col * 104 + s * 8]);
                acc[nt] = __builtin_amdgcn_mfma_f32_32x32x16_bf16(av, bv, acc[nt], 0, 0, 0);
            }
        }
        __builtin_amdgcn_s_setprio(0);

        // ---------- epilogue: b1-add + relu + W2-dot, packed f32 pairs ----------
        f32x2 part2[8];
        #pragma unroll
        for (int i = 0; i < 8; ++i) { part2[i][0] = 0.f; part2[i][1] = 0.f; }
        #pragma unroll
        for (int nt = 0; nt < 8; ++nt) {
            const f32x2 w2v = {w2r[nt], w2r[nt]};
            const f32x2 b1v = {b1r[nt], b1r[nt]};
            const f32x2 z = {0.f, 0.f};
            #pragma unroll
            for (int i = 0; i < 8; ++i) {
                f32x2 h = {acc[nt][2 * i], acc[nt][2 * i + 1]};
                h = __builtin_elementwise_max(h + b1v, z);
                part2[i] += h * w2v;
            }
        }

        // ---------- split-register butterfly reduce over 32 lanes ----------
        // (operates on float2 pairs; element r = part2[r>>1][r&1])
        const int b_ = (l31 >> 4) & 1, c_ = (l31 >> 3) & 1,
                  d_ = (l31 >> 2) & 1, e_ = (l31 >> 1) & 1;
        f32x2 q1[4], q2[2], q3;
        float p4, p5;
        #pragma unroll
        for (int i = 0; i < 4; ++i) {          // exchange r<8 vs r>=8
            f32x2 keep = b_ ? part2[4 + i] : part2[i];
            f32x2 send = b_ ? part2[i]     : part2[4 + i];
            f32x2 got;
            got[0] = __shfl_xor(send[0], 16, 64);
            got[1] = __shfl_xor(send[1], 16, 64);
            q1[i] = keep + got;
        }
        #pragma unroll
        for (int i = 0; i < 2; ++i) {          // exchange r<4 vs r>=4
            f32x2 keep = c_ ? q1[2 + i] : q1[i];
            f32x2 send = c_ ? q1[i]     : q1[2 + i];
            f32x2 got;
            got[0] = __shfl_xor(send[0], 8, 64);
            got[1] = __shfl_xor(send[1], 8, 64);
            q2[i] = keep + got;
        }
        {                                       // exchange r<2 vs r>=2
            f32x2 keep = d_ ? q2[1] : q2[0];
            f32x2 send = d_ ? q2[0] : q2[1];
            f32x2 got;
            got[0] = __shfl_xor(send[0], 4, 64);
            got[1] = __shfl_xor(send[1], 4, 64);
            q3 = keep + got;
        }
        {                                       // exchange r=0 vs r=1 (inside float2)
            float keep = e_ ? q3[1] : q3[0];
            float send = e_ ? q3[0] : q3[1];
            p4 = keep + __shfl_xor(send, 2, 64);
        }
        p5 = p4 + __shfl_xor(p4, 1, 64);
        // even lane l31 holds the full sum for r = l31>>1 (row = (r&3)+8*(r>>2)+4*hi)

        // ---------- coalesced store via LDS transpose (512 B staging) ----------
        if (!(lane & 1)) {
            const int r = l31 >> 1;
            outbuf[wv * 32 + 4 * hi + (r & 3) + 8 * (r >> 2)] = p5 + b2v;
        }
        asm volatile("s_waitcnt lgkmcnt(0)" ::: "memory");
        if (lane < 32) {
            out[tile * 128 + wv * 32 + lane] = outbuf[wv * 32 + lane];
        }
    }
#undef LOADIDX
}

extern "C" void kernel_launch(void* const* d_in, const int* in_sizes, int n_in,
                              void* d_out, int out_size, void* d_ws, size_t ws_size,
                              hipStream_t stream) {
    const int*   gidx = (const int*)d_in[0];
    const int*   cidx = (const int*)d_in[1];
    const int*   pidx = (const int*)d_in[2];
    const int*   plen = (const int*)d_in[3];
    const int*   aidx = (const int*)d_in[4];
    const int*   alen = (const int*)d_in[5];
    const float* gt   = (const float*)d_in[6];
    const float* ct   = (const float*)d_in[7];
    const float* W1   = (const float*)d_in[8];
    const float* b1   = (const float*)d_in[9];
    const float* W2   = (const float*)d_in[10];
    const float* b2   = (const float*)d_in[11];
    float* out = (float*)d_out;
    unsigned short* ws = (unsigned short*)d_ws;

    const int B = in_sizes[0] / 5;          // 1048576
    prep_kernel<<<96, 256, 0, stream>>>(gt, ct, W1, ws);

    const int tilesTotal = B / 128;         // 8192 block-tiles of 128 rows
    int tpb = 16;                           // 512 persistent blocks = 2/CU
    while (tpb > 1 && (tilesTotal % tpb)) tpb >>= 1;
    const int blocks = tilesTotal / tpb;
    wordle_kernel<<<blocks, 256, 0, stream>>>(gidx, cidx, pidx, plen, aidx, alen,
                                              b1, W2, b2, ws, out, tpb);
}